// Round 1
// baseline (16363.551 us; speedup 1.0000x reference)
//
#include <hip/hip_runtime.h>
#include <math.h>

#define Bsz  4
#define Nseq 2048
#define Dm   1024
#define Hh   16
#define DHd  64
#define DFFd 4096
#define EPSv 1e-5f

// ---------------------------------------------------------------------------
// LayerNorm: one 256-thread block per row of Dm=1024 floats.
// ---------------------------------------------------------------------------
__global__ __launch_bounds__(256) void ln_kernel(
    const float* __restrict__ x, const float* __restrict__ g,
    const float* __restrict__ b, float* __restrict__ out)
{
    const int row = blockIdx.x;
    const int tid = threadIdx.x;
    const float* xr = x + (size_t)row * Dm;
    float* outr = out + (size_t)row * Dm;

    float4 v = ((const float4*)xr)[tid];           // 256 * 4 = 1024
    __shared__ float red[5];

    float s = v.x + v.y + v.z + v.w;
    for (int off = 32; off; off >>= 1) s += __shfl_down(s, off, 64);
    int lane = tid & 63, wv = tid >> 6;
    if (lane == 0) red[wv] = s;
    __syncthreads();
    if (tid == 0) red[4] = (red[0] + red[1] + red[2] + red[3]) * (1.0f / Dm);
    __syncthreads();
    const float mean = red[4];

    float dx = v.x - mean, dy = v.y - mean, dz = v.z - mean, dw = v.w - mean;
    float s2 = dx*dx + dy*dy + dz*dz + dw*dw;
    for (int off = 32; off; off >>= 1) s2 += __shfl_down(s2, off, 64);
    if (lane == 0) red[wv] = s2;
    __syncthreads();
    if (tid == 0) red[4] = rsqrtf((red[0] + red[1] + red[2] + red[3]) * (1.0f / Dm) + EPSv);
    __syncthreads();
    const float inv = red[4];

    float4 gv = ((const float4*)g)[tid];
    float4 bv = ((const float4*)b)[tid];
    float4 o;
    o.x = dx * inv * gv.x + bv.x;
    o.y = dy * inv * gv.y + bv.y;
    o.z = dz * inv * gv.z + bv.z;
    o.w = dw * inv * gv.w + bv.w;
    ((float4*)outr)[tid] = o;
}

// ---------------------------------------------------------------------------
// Generic fp32 GEMM: C[M,N] = A[M,K] @ B[K,N] + bias, optional gelu/residual.
// 64x64 block tile, BK=16, 256 threads, 4x4 microtile. M,N %64==0, K %16==0.
// EPI: 0 = bias, 1 = bias + exact GELU, 2 = bias + residual
// ---------------------------------------------------------------------------
template<int EPI>
__global__ __launch_bounds__(256) void gemm_kernel(
    const float* __restrict__ A, const float* __restrict__ Bw,
    const float* __restrict__ bias, const float* __restrict__ res,
    float* __restrict__ C, int M, int Nn, int K)
{
    __shared__ float As[16][65];    // [k][m]
    __shared__ float Bs[16][68];    // [k][n] (pad keeps float4 align)

    const int tid = threadIdx.x;
    const int bm = blockIdx.y * 64, bn = blockIdx.x * 64;
    const int tx = tid & 15, ty = tid >> 4;

    const int rowA = tid >> 2, c4A = (tid & 3) * 4;
    const int rowB = tid >> 4, c4B = (tid & 15) * 4;
    const float* Aptr = A + (size_t)(bm + rowA) * K + c4A;
    const float* Bptr = Bw + (size_t)rowB * Nn + bn + c4B;

    float acc[4][4] = {};

    for (int k0 = 0; k0 < K; k0 += 16) {
        float4 av = *(const float4*)(Aptr + k0);
        float4 bv = *(const float4*)(Bptr + (size_t)k0 * Nn);
        As[c4A + 0][rowA] = av.x;
        As[c4A + 1][rowA] = av.y;
        As[c4A + 2][rowA] = av.z;
        As[c4A + 3][rowA] = av.w;
        *(float4*)&Bs[rowB][c4B] = bv;
        __syncthreads();
#pragma unroll
        for (int kk = 0; kk < 16; kk++) {
            float a0 = As[kk][ty*4+0], a1 = As[kk][ty*4+1];
            float a2 = As[kk][ty*4+2], a3 = As[kk][ty*4+3];
            float b0 = Bs[kk][tx*4+0], b1 = Bs[kk][tx*4+1];
            float b2 = Bs[kk][tx*4+2], b3 = Bs[kk][tx*4+3];
            acc[0][0] += a0*b0; acc[0][1] += a0*b1; acc[0][2] += a0*b2; acc[0][3] += a0*b3;
            acc[1][0] += a1*b0; acc[1][1] += a1*b1; acc[1][2] += a1*b2; acc[1][3] += a1*b3;
            acc[2][0] += a2*b0; acc[2][1] += a2*b1; acc[2][2] += a2*b2; acc[2][3] += a2*b3;
            acc[3][0] += a3*b0; acc[3][1] += a3*b1; acc[3][2] += a3*b2; acc[3][3] += a3*b3;
        }
        __syncthreads();
    }

    float4 biasv = *(const float4*)&bias[bn + tx*4];
#pragma unroll
    for (int i = 0; i < 4; i++) {
        const size_t r = (size_t)(bm + ty*4 + i);
        float4 o;
        o.x = acc[i][0] + biasv.x;
        o.y = acc[i][1] + biasv.y;
        o.z = acc[i][2] + biasv.z;
        o.w = acc[i][3] + biasv.w;
        if (EPI == 1) {
            o.x = 0.5f * o.x * (1.0f + erff(o.x * 0.70710678118f));
            o.y = 0.5f * o.y * (1.0f + erff(o.y * 0.70710678118f));
            o.z = 0.5f * o.z * (1.0f + erff(o.z * 0.70710678118f));
            o.w = 0.5f * o.w * (1.0f + erff(o.w * 0.70710678118f));
        }
        if (EPI == 2) {
            float4 rv = *(const float4*)&res[r * Nn + bn + tx*4];
            o.x += rv.x; o.y += rv.y; o.z += rv.z; o.w += rv.w;
        }
        *(float4*)&C[r * Nn + bn + tx*4] = o;
    }
}

// ---------------------------------------------------------------------------
// Attention: one 256-thread block per (b,h,n) row. Logits in LDS (8KB).
// qkv layout: [B, N, 3*Dm] with col = which*Dm + h*DHd + d.
// ---------------------------------------------------------------------------
__global__ __launch_bounds__(256) void attn_kernel(
    const float* __restrict__ qkv, const float* __restrict__ sbias,
    float* __restrict__ out)
{
    __shared__ float sq[DHd];
    __shared__ float sl[Nseq];
    __shared__ float red[4];
    __shared__ float sacc[256];

    const int tid = threadIdx.x;
    const int idx = blockIdx.x;               // ((b*Hh + h) << 11) | n
    const int n = idx & (Nseq - 1);
    const int h = (idx >> 11) & (Hh - 1);
    const int b = idx >> 15;

    const size_t qoff = ((size_t)(b * Nseq + n)) * (3 * Dm) + h * DHd;
    if (tid < DHd) sq[tid] = qkv[qoff + tid];
    __syncthreads();

    const float scale = 0.125f;               // 1/sqrt(64)
    const float* biasrow = sbias + ((size_t)h * Nseq + n) * Nseq;

    float mx = -1e30f;
    for (int m = tid; m < Nseq; m += 256) {
        const float* kp = qkv + ((size_t)(b * Nseq + m)) * (3 * Dm) + Dm + h * DHd;
        float dot = 0.f;
#pragma unroll
        for (int d4 = 0; d4 < 16; d4++) {
            float4 kv = ((const float4*)kp)[d4];
            dot += sq[d4*4+0]*kv.x + sq[d4*4+1]*kv.y + sq[d4*4+2]*kv.z + sq[d4*4+3]*kv.w;
        }
        float lg = dot * scale + biasrow[m];
        sl[m] = lg;
        mx = fmaxf(mx, lg);
    }
    for (int off = 32; off; off >>= 1) mx = fmaxf(mx, __shfl_down(mx, off, 64));
    const int lane = tid & 63, wv = tid >> 6;
    if (lane == 0) red[wv] = mx;
    __syncthreads();
    mx = fmaxf(fmaxf(red[0], red[1]), fmaxf(red[2], red[3]));
    __syncthreads();

    float sum = 0.f;
    for (int m = tid; m < Nseq; m += 256) {
        float p = __expf(sl[m] - mx);
        sl[m] = p;
        sum += p;
    }
    for (int off = 32; off; off >>= 1) sum += __shfl_down(sum, off, 64);
    if (lane == 0) red[wv] = sum;
    __syncthreads();
    const float inv = 1.0f / (red[0] + red[1] + red[2] + red[3]);

    // PV: thread (seg,d) accumulates over its 512 m's for dim d.
    const int d = tid & 63, seg = tid >> 6;
    const float* vbase = qkv + ((size_t)b * Nseq) * (3 * Dm) + 2 * Dm + h * DHd + d;
    float acc = 0.f;
    const int m0 = seg * 512;
    for (int m = m0; m < m0 + 512; m++) {
        acc += sl[m] * vbase[(size_t)m * (3 * Dm)];
    }
    sacc[tid] = acc;
    __syncthreads();
    if (seg == 0) {
        float r = (sacc[d] + sacc[64 + d] + sacc[128 + d] + sacc[192 + d]) * inv;
        out[((size_t)(b * Nseq + n)) * Dm + h * DHd + d] = r;
    }
}

// ---------------------------------------------------------------------------
// Launch. Workspace layout (160 MB total):
//   [0,   32MB)  normed / h_norm / attn_out (time-shared)
//   [32, 128MB)  qkv  (96MB); later reused (with next region) for ff hidden
//   [128,160MB)  attn_out
//   ff hidden h: [32, 160MB) (qkv+attn dead by then)
// x1 (post-attention residual) lives in d_out; FF2 adds into it in place.
// ---------------------------------------------------------------------------
extern "C" void kernel_launch(void* const* d_in, const int* in_sizes, int n_in,
                              void* d_out, int out_size, void* d_ws, size_t ws_size,
                              hipStream_t stream)
{
    const float* x     = (const float*)d_in[0];
    const float* sbias = (const float*)d_in[1];
    const float* ln1g  = (const float*)d_in[2];
    const float* ln1b  = (const float*)d_in[3];
    const float* ln2g  = (const float*)d_in[4];
    const float* ln2b  = (const float*)d_in[5];
    const float* W_qkv = (const float*)d_in[6];
    const float* b_qkv = (const float*)d_in[7];
    const float* W_out = (const float*)d_in[8];
    const float* b_out = (const float*)d_in[9];
    const float* W_ff1 = (const float*)d_in[10];
    const float* b_ff1 = (const float*)d_in[11];
    const float* W_ff2 = (const float*)d_in[12];
    const float* b_ff2 = (const float*)d_in[13];
    float* out = (float*)d_out;

    char* ws = (char*)d_ws;
    float* normed = (float*)ws;                               // 32MB
    float* qkv    = (float*)(ws + 32ull * 1024 * 1024);       // 96MB
    float* attn   = (float*)(ws + 128ull * 1024 * 1024);      // 32MB
    float* hbuf   = (float*)(ws + 32ull * 1024 * 1024);       // 128MB (reuse)

    const int M = Bsz * Nseq;   // 8192

    // 1. ln1(x) -> normed
    ln_kernel<<<M, 256, 0, stream>>>(x, ln1g, ln1b, normed);
    // 2. qkv = normed @ W_qkv + b_qkv
    gemm_kernel<0><<<dim3(3 * Dm / 64, M / 64), 256, 0, stream>>>(
        normed, W_qkv, b_qkv, nullptr, qkv, M, 3 * Dm, Dm);
    // 3. attention -> attn (B,N,D)
    attn_kernel<<<Bsz * Hh * Nseq, 256, 0, stream>>>(qkv, sbias, attn);
    // 4. x1 = x + attn @ W_out + b_out  -> d_out
    gemm_kernel<2><<<dim3(Dm / 64, M / 64), 256, 0, stream>>>(
        attn, W_out, b_out, x, out, M, Dm, Dm);
    // 5. ln2(x1) -> normed
    ln_kernel<<<M, 256, 0, stream>>>(out, ln2g, ln2b, normed);
    // 6. h = gelu(normed @ W_ff1 + b_ff1)
    gemm_kernel<1><<<dim3(DFFd / 64, M / 64), 256, 0, stream>>>(
        normed, W_ff1, b_ff1, nullptr, hbuf, M, DFFd, Dm);
    // 7. out = x1 + h @ W_ff2 + b_ff2   (in-place on d_out)
    gemm_kernel<2><<<dim3(Dm / 64, M / 64), 256, 0, stream>>>(
        hbuf, W_ff2, b_ff2, out, out, M, Dm, DFFd);
}

// Round 2
// 4609.944 us; speedup vs baseline: 3.5496x; 3.5496x over previous
//
#include <hip/hip_runtime.h>
#include <math.h>

#define Bsz  4
#define Nseq 2048
#define Dm   1024
#define Hh   16
#define DHd  64
#define DFFd 4096
#define EPSv 1e-5f

// ---------------------------------------------------------------------------
// LayerNorm: one 256-thread block per row of Dm=1024 floats.
// ---------------------------------------------------------------------------
__global__ __launch_bounds__(256) void ln_kernel(
    const float* __restrict__ x, const float* __restrict__ g,
    const float* __restrict__ b, float* __restrict__ out)
{
    const int row = blockIdx.x;
    const int tid = threadIdx.x;
    const float* xr = x + (size_t)row * Dm;
    float* outr = out + (size_t)row * Dm;

    float4 v = ((const float4*)xr)[tid];           // 256 * 4 = 1024
    __shared__ float red[5];

    float s = v.x + v.y + v.z + v.w;
    for (int off = 32; off; off >>= 1) s += __shfl_down(s, off, 64);
    int lane = tid & 63, wv = tid >> 6;
    if (lane == 0) red[wv] = s;
    __syncthreads();
    if (tid == 0) red[4] = (red[0] + red[1] + red[2] + red[3]) * (1.0f / Dm);
    __syncthreads();
    const float mean = red[4];

    float dx = v.x - mean, dy = v.y - mean, dz = v.z - mean, dw = v.w - mean;
    float s2 = dx*dx + dy*dy + dz*dz + dw*dw;
    for (int off = 32; off; off >>= 1) s2 += __shfl_down(s2, off, 64);
    if (lane == 0) red[wv] = s2;
    __syncthreads();
    if (tid == 0) red[4] = rsqrtf((red[0] + red[1] + red[2] + red[3]) * (1.0f / Dm) + EPSv);
    __syncthreads();
    const float inv = red[4];

    float4 gv = ((const float4*)g)[tid];
    float4 bv = ((const float4*)b)[tid];
    float4 o;
    o.x = dx * inv * gv.x + bv.x;
    o.y = dy * inv * gv.y + bv.y;
    o.z = dz * inv * gv.z + bv.z;
    o.w = dw * inv * gv.w + bv.w;
    ((float4*)outr)[tid] = o;
}

// ---------------------------------------------------------------------------
// Generic fp32 GEMM: C[M,N] = A[M,K] @ B[K,N] + bias, optional gelu/residual.
// 64x64 block tile, BK=16, 256 threads, 4x4 microtile. M,N %64==0, K %16==0.
// EPI: 0 = bias, 1 = bias + exact GELU, 2 = bias + residual
// ---------------------------------------------------------------------------
template<int EPI>
__global__ __launch_bounds__(256) void gemm_kernel(
    const float* __restrict__ A, const float* __restrict__ Bw,
    const float* __restrict__ bias, const float* __restrict__ res,
    float* __restrict__ C, int M, int Nn, int K)
{
    __shared__ float As[16][65];    // [k][m]
    __shared__ float Bs[16][68];    // [k][n] (pad keeps float4 align)

    const int tid = threadIdx.x;
    const int bm = blockIdx.y * 64, bn = blockIdx.x * 64;
    const int tx = tid & 15, ty = tid >> 4;

    const int rowA = tid >> 2, c4A = (tid & 3) * 4;
    const int rowB = tid >> 4, c4B = (tid & 15) * 4;
    const float* Aptr = A + (size_t)(bm + rowA) * K + c4A;
    const float* Bptr = Bw + (size_t)rowB * Nn + bn + c4B;

    float acc[4][4] = {};

    for (int k0 = 0; k0 < K; k0 += 16) {
        float4 av = *(const float4*)(Aptr + k0);
        float4 bv = *(const float4*)(Bptr + (size_t)k0 * Nn);
        As[c4A + 0][rowA] = av.x;
        As[c4A + 1][rowA] = av.y;
        As[c4A + 2][rowA] = av.z;
        As[c4A + 3][rowA] = av.w;
        *(float4*)&Bs[rowB][c4B] = bv;
        __syncthreads();
#pragma unroll
        for (int kk = 0; kk < 16; kk++) {
            float a0 = As[kk][ty*4+0], a1 = As[kk][ty*4+1];
            float a2 = As[kk][ty*4+2], a3 = As[kk][ty*4+3];
            float b0 = Bs[kk][tx*4+0], b1 = Bs[kk][tx*4+1];
            float b2 = Bs[kk][tx*4+2], b3 = Bs[kk][tx*4+3];
            acc[0][0] += a0*b0; acc[0][1] += a0*b1; acc[0][2] += a0*b2; acc[0][3] += a0*b3;
            acc[1][0] += a1*b0; acc[1][1] += a1*b1; acc[1][2] += a1*b2; acc[1][3] += a1*b3;
            acc[2][0] += a2*b0; acc[2][1] += a2*b1; acc[2][2] += a2*b2; acc[2][3] += a2*b3;
            acc[3][0] += a3*b0; acc[3][1] += a3*b1; acc[3][2] += a3*b2; acc[3][3] += a3*b3;
        }
        __syncthreads();
    }

    float4 biasv = *(const float4*)&bias[bn + tx*4];
#pragma unroll
    for (int i = 0; i < 4; i++) {
        const size_t r = (size_t)(bm + ty*4 + i);
        float4 o;
        o.x = acc[i][0] + biasv.x;
        o.y = acc[i][1] + biasv.y;
        o.z = acc[i][2] + biasv.z;
        o.w = acc[i][3] + biasv.w;
        if (EPI == 1) {
            o.x = 0.5f * o.x * (1.0f + erff(o.x * 0.70710678118f));
            o.y = 0.5f * o.y * (1.0f + erff(o.y * 0.70710678118f));
            o.z = 0.5f * o.z * (1.0f + erff(o.z * 0.70710678118f));
            o.w = 0.5f * o.w * (1.0f + erff(o.w * 0.70710678118f));
        }
        if (EPI == 2) {
            float4 rv = *(const float4*)&res[r * Nn + bn + tx*4];
            o.x += rv.x; o.y += rv.y; o.z += rv.z; o.w += rv.w;
        }
        *(float4*)&C[r * Nn + bn + tx*4] = o;
    }
}

// ---------------------------------------------------------------------------
// Flash-style attention, fp32 vector ALU.
// One 256-thread block per (h, q-tile of 64, b). 64x64 K/V tiles in LDS.
// Online softmax; P round-trips through LDS (reuses K buffer, transposed).
// qkv layout: [B, N, 3*Dm], col = which*Dm + h*DHd + d.
// ---------------------------------------------------------------------------
__global__ __launch_bounds__(256) void fattn_kernel(
    const float* __restrict__ qkv, const float* __restrict__ sbias,
    float* __restrict__ out)
{
    __shared__ float Qs[64][68];   // [d][i]  (transposed)
    __shared__ float Ks[64][68];   // [d][m]  (transposed); reused as Ps[m][i]
    __shared__ float Vs[64][68];   // [m][d]

    const int tid = threadIdx.x;
    const int idx = blockIdx.x;         // ((h*32 + qt)*4 + b)
    const int b  = idx & 3;
    const int g  = idx >> 2;
    const int qt = g & 31;
    const int h  = g >> 5;
    const int n0 = qt * 64;

    const int tx = tid & 15, ty = tid >> 4;
    const size_t qkbase = (size_t)b * Nseq * (3 * Dm);

    // ---- load Q tile (transposed into Qs[d][i]) ----
    for (int f = tid; f < 1024; f += 256) {
        const int i = f >> 4, d4 = (f & 15) * 4;
        float4 v = *(const float4*)&qkv[qkbase + (size_t)(n0 + i) * (3*Dm) + h*DHd + d4];
        Qs[d4+0][i] = v.x; Qs[d4+1][i] = v.y; Qs[d4+2][i] = v.z; Qs[d4+3][i] = v.w;
    }

    float O[4][4] = {};
    float mrow[4] = {-1e30f, -1e30f, -1e30f, -1e30f};
    float lrow[4] = {};

    for (int kt = 0; kt < 32; kt++) {
        __syncthreads();               // prev-iter LDS reads complete
        // ---- stage K (transposed) and V tiles ----
        for (int f = tid; f < 1024; f += 256) {
            const int m = f >> 4, d4 = (f & 15) * 4;
            const size_t base = qkbase + (size_t)(kt*64 + m) * (3*Dm) + h*DHd + d4;
            float4 kv = *(const float4*)&qkv[base + Dm];
            float4 vv = *(const float4*)&qkv[base + 2*Dm];
            Ks[d4+0][m] = kv.x; Ks[d4+1][m] = kv.y; Ks[d4+2][m] = kv.z; Ks[d4+3][m] = kv.w;
            *(float4*)&Vs[m][d4] = vv;
        }
        __syncthreads();

        // ---- S tile: 64x64x64 register-blocked GEMM ----
        float S[4][4] = {};
#pragma unroll 16
        for (int d = 0; d < 64; d++) {
            float4 av = *(const float4*)&Qs[d][ty*4];
            float4 bv = *(const float4*)&Ks[d][tx*4];
            S[0][0] += av.x*bv.x; S[0][1] += av.x*bv.y; S[0][2] += av.x*bv.z; S[0][3] += av.x*bv.w;
            S[1][0] += av.y*bv.x; S[1][1] += av.y*bv.y; S[1][2] += av.y*bv.z; S[1][3] += av.y*bv.w;
            S[2][0] += av.z*bv.x; S[2][1] += av.z*bv.y; S[2][2] += av.z*bv.z; S[2][3] += av.z*bv.w;
            S[3][0] += av.w*bv.x; S[3][1] += av.w*bv.y; S[3][2] += av.w*bv.z; S[3][3] += av.w*bv.w;
        }

        // ---- scale + structural bias ----
#pragma unroll
        for (int i = 0; i < 4; i++) {
            float4 bb = *(const float4*)&sbias[((size_t)h*Nseq + (n0+ty*4+i))*Nseq + kt*64 + tx*4];
            S[i][0] = S[i][0]*0.125f + bb.x;
            S[i][1] = S[i][1]*0.125f + bb.y;
            S[i][2] = S[i][2]*0.125f + bb.z;
            S[i][3] = S[i][3]*0.125f + bb.w;
        }

        // ---- online softmax (row state replicated across the 16 tx lanes) ----
#pragma unroll
        for (int i = 0; i < 4; i++) {
            float tmax = fmaxf(fmaxf(S[i][0], S[i][1]), fmaxf(S[i][2], S[i][3]));
            tmax = fmaxf(tmax, __shfl_xor(tmax, 1, 64));
            tmax = fmaxf(tmax, __shfl_xor(tmax, 2, 64));
            tmax = fmaxf(tmax, __shfl_xor(tmax, 4, 64));
            tmax = fmaxf(tmax, __shfl_xor(tmax, 8, 64));
            const float mnew = fmaxf(mrow[i], tmax);
            const float alpha = __expf(mrow[i] - mnew);
            float ssum = 0.f;
#pragma unroll
            for (int j = 0; j < 4; j++) {
                S[i][j] = __expf(S[i][j] - mnew);
                ssum += S[i][j];
            }
            ssum += __shfl_xor(ssum, 1, 64);
            ssum += __shfl_xor(ssum, 2, 64);
            ssum += __shfl_xor(ssum, 4, 64);
            ssum += __shfl_xor(ssum, 8, 64);
            lrow[i] = lrow[i]*alpha + ssum;
            mrow[i] = mnew;
            O[i][0] *= alpha; O[i][1] *= alpha; O[i][2] *= alpha; O[i][3] *= alpha;
        }

        __syncthreads();               // everyone done reading Ks
        // ---- write P transposed into Ks: Ps[m][i] ----
#pragma unroll
        for (int i = 0; i < 4; i++)
#pragma unroll
            for (int j = 0; j < 4; j++)
                Ks[tx*4+j][ty*4+i] = S[i][j];
        __syncthreads();

        // ---- O += P x V : 64x64x64 register-blocked GEMM ----
#pragma unroll 16
        for (int m = 0; m < 64; m++) {
            float4 av = *(const float4*)&Ks[m][ty*4];   // P[m][rows]
            float4 bv = *(const float4*)&Vs[m][tx*4];   // V[m][dims]
            O[0][0] += av.x*bv.x; O[0][1] += av.x*bv.y; O[0][2] += av.x*bv.z; O[0][3] += av.x*bv.w;
            O[1][0] += av.y*bv.x; O[1][1] += av.y*bv.y; O[1][2] += av.y*bv.z; O[1][3] += av.y*bv.w;
            O[2][0] += av.z*bv.x; O[2][1] += av.z*bv.y; O[2][2] += av.z*bv.z; O[2][3] += av.z*bv.w;
            O[3][0] += av.w*bv.x; O[3][1] += av.w*bv.y; O[3][2] += av.w*bv.z; O[3][3] += av.w*bv.w;
        }
    }

    // ---- normalize and write (B,N,D) ----
#pragma unroll
    for (int i = 0; i < 4; i++) {
        const float invl = 1.0f / lrow[i];
        float4 o;
        o.x = O[i][0]*invl; o.y = O[i][1]*invl; o.z = O[i][2]*invl; o.w = O[i][3]*invl;
        *(float4*)&out[(size_t)(b*Nseq + n0 + ty*4 + i)*Dm + h*DHd + tx*4] = o;
    }
}

// ---------------------------------------------------------------------------
// Launch. Workspace layout (160 MB total):
//   [0,   32MB)  normed / h_norm (time-shared)
//   [32, 128MB)  qkv  (96MB); later reused for ff hidden
//   [128,160MB)  attn_out
// x1 (post-attention residual) lives in d_out; FF2 adds into it in place.
// ---------------------------------------------------------------------------
extern "C" void kernel_launch(void* const* d_in, const int* in_sizes, int n_in,
                              void* d_out, int out_size, void* d_ws, size_t ws_size,
                              hipStream_t stream)
{
    const float* x     = (const float*)d_in[0];
    const float* sbias = (const float*)d_in[1];
    const float* ln1g  = (const float*)d_in[2];
    const float* ln1b  = (const float*)d_in[3];
    const float* ln2g  = (const float*)d_in[4];
    const float* ln2b  = (const float*)d_in[5];
    const float* W_qkv = (const float*)d_in[6];
    const float* b_qkv = (const float*)d_in[7];
    const float* W_out = (const float*)d_in[8];
    const float* b_out = (const float*)d_in[9];
    const float* W_ff1 = (const float*)d_in[10];
    const float* b_ff1 = (const float*)d_in[11];
    const float* W_ff2 = (const float*)d_in[12];
    const float* b_ff2 = (const float*)d_in[13];
    float* out = (float*)d_out;

    char* ws = (char*)d_ws;
    float* normed = (float*)ws;                               // 32MB
    float* qkv    = (float*)(ws + 32ull * 1024 * 1024);       // 96MB
    float* attn   = (float*)(ws + 128ull * 1024 * 1024);      // 32MB
    float* hbuf   = (float*)(ws + 32ull * 1024 * 1024);       // 128MB (reuse)

    const int M = Bsz * Nseq;   // 8192

    // 1. ln1(x) -> normed
    ln_kernel<<<M, 256, 0, stream>>>(x, ln1g, ln1b, normed);
    // 2. qkv = normed @ W_qkv + b_qkv
    gemm_kernel<0><<<dim3(3 * Dm / 64, M / 64), 256, 0, stream>>>(
        normed, W_qkv, b_qkv, nullptr, qkv, M, 3 * Dm, Dm);
    // 3. flash attention -> attn (B,N,D)
    fattn_kernel<<<Hh * 32 * Bsz, 256, 0, stream>>>(qkv, sbias, attn);
    // 4. x1 = x + attn @ W_out + b_out  -> d_out
    gemm_kernel<2><<<dim3(Dm / 64, M / 64), 256, 0, stream>>>(
        attn, W_out, b_out, x, out, M, Dm, Dm);
    // 5. ln2(x1) -> normed
    ln_kernel<<<M, 256, 0, stream>>>(out, ln2g, ln2b, normed);
    // 6. h = gelu(normed @ W_ff1 + b_ff1)
    gemm_kernel<1><<<dim3(DFFd / 64, M / 64), 256, 0, stream>>>(
        normed, W_ff1, b_ff1, nullptr, hbuf, M, DFFd, Dm);
    // 7. out = x1 + h @ W_ff2 + b_ff2   (in-place on d_out)
    gemm_kernel<2><<<dim3(Dm / 64, M / 64), 256, 0, stream>>>(
        hbuf, W_ff2, b_ff2, out, out, M, Dm, DFFd);
}

// Round 3
// 1823.435 us; speedup vs baseline: 8.9740x; 2.5282x over previous
//
#include <hip/hip_runtime.h>
#include <math.h>

#define Bsz  4
#define Nseq 2048
#define Dm   1024
#define Hh   16
#define DHd  64
#define DFFd 4096
#define EPSv 1e-5f

typedef unsigned short u16;
typedef __attribute__((ext_vector_type(8))) short bf16x8;   // 8 bf16 = 4 VGPRs
typedef __attribute__((ext_vector_type(4))) float f32x4;

__device__ inline u16 f2bf(float f) {
    union { float f; unsigned int u; } v; v.f = f;
    unsigned int r = v.u + 0x7fffu + ((v.u >> 16) & 1u);   // round-to-nearest-even
    return (u16)(r >> 16);
}

// ---------------------------------------------------------------------------
// LayerNorm: one 256-thread block per row of Dm=1024 floats. OBF: bf16 out.
// ---------------------------------------------------------------------------
template<int OBF>
__global__ __launch_bounds__(256) void ln_kernel(
    const float* __restrict__ x, const float* __restrict__ g,
    const float* __restrict__ b, void* __restrict__ outv)
{
    const int row = blockIdx.x;
    const int tid = threadIdx.x;
    const float* xr = x + (size_t)row * Dm;

    float4 v = ((const float4*)xr)[tid];
    __shared__ float red[5];

    float s = v.x + v.y + v.z + v.w;
    for (int off = 32; off; off >>= 1) s += __shfl_down(s, off, 64);
    int lane = tid & 63, wv = tid >> 6;
    if (lane == 0) red[wv] = s;
    __syncthreads();
    if (tid == 0) red[4] = (red[0] + red[1] + red[2] + red[3]) * (1.0f / Dm);
    __syncthreads();
    const float mean = red[4];

    float dx = v.x - mean, dy = v.y - mean, dz = v.z - mean, dw = v.w - mean;
    float s2 = dx*dx + dy*dy + dz*dz + dw*dw;
    for (int off = 32; off; off >>= 1) s2 += __shfl_down(s2, off, 64);
    if (lane == 0) red[wv] = s2;
    __syncthreads();
    if (tid == 0) red[4] = rsqrtf((red[0] + red[1] + red[2] + red[3]) * (1.0f / Dm) + EPSv);
    __syncthreads();
    const float inv = red[4];

    float4 gv = ((const float4*)g)[tid];
    float4 bv = ((const float4*)b)[tid];
    float ox = dx * inv * gv.x + bv.x;
    float oy = dy * inv * gv.y + bv.y;
    float oz = dz * inv * gv.z + bv.z;
    float ow = dw * inv * gv.w + bv.w;
    if (OBF) {
        ushort4 o; o.x = f2bf(ox); o.y = f2bf(oy); o.z = f2bf(oz); o.w = f2bf(ow);
        ((ushort4*)((u16*)outv + (size_t)row * Dm))[tid] = o;
    } else {
        float4 o; o.x = ox; o.y = oy; o.z = oz; o.w = ow;
        ((float4*)((float*)outv + (size_t)row * Dm))[tid] = o;
    }
}

// ---------------------------------------------------------------------------
// Weight convert+transpose: W[K][N] fp32 -> Wt[N][K] bf16. 32x32 LDS tiles.
// ---------------------------------------------------------------------------
__global__ __launch_bounds__(256) void tcvt_kernel(
    const float* __restrict__ W, u16* __restrict__ Wt, int K, int N)
{
    __shared__ float t[32][33];
    const int k0 = blockIdx.y * 32, n0 = blockIdx.x * 32;
    const int tx = threadIdx.x & 31, ty = threadIdx.x >> 5;   // ty 0..7
#pragma unroll
    for (int i = 0; i < 4; i++)
        t[ty + i*8][tx] = W[(size_t)(k0 + ty + i*8) * N + n0 + tx];
    __syncthreads();
#pragma unroll
    for (int i = 0; i < 4; i++)
        Wt[(size_t)(n0 + ty + i*8) * K + k0 + tx] = f2bf(t[tx][ty + i*8]);
}

// ---------------------------------------------------------------------------
// bf16 MFMA GEMM: C[M,Nn] = A[M,K](bf16) x Bt[Nn,K](bf16) + bias, epilogue.
// 128x128 tile, BK=32, 256 threads (4 waves, each 64x64 via 4x4 mfma tiles).
// Staging via global_load_lds(16B); LDS chunk XOR-swizzle (c ^ ((r>>1)&3)).
// EPI: 0 = bias -> f32 | 1 = bias + res(f32) -> f32 | 2 = bias + GELU -> bf16
// ---------------------------------------------------------------------------
template<int EPI>
__global__ __launch_bounds__(256) void bgemm_kernel(
    const u16* __restrict__ A, const u16* __restrict__ Bt,
    const float* __restrict__ bias, const float* __restrict__ res,
    void* __restrict__ Cout, int M, int Nn, int K)
{
    __shared__ u16 Asl[128 * 32];   // 8 KB, row-major [r][32], chunks swizzled
    __shared__ u16 Bsl[128 * 32];   // 8 KB

    const int tid  = threadIdx.x;
    const int lane = tid & 63;
    const int w    = tid >> 6;              // wave 0..3
    const int bm   = blockIdx.y * 128;
    const int bn   = blockIdx.x * 128;
    const int wm   = (w & 1) * 64;
    const int wn   = (w >> 1) * 64;

    // ---- staging addresses: wave w stages rows [w*32, w*32+32) of A and B ----
    const int r0 = w * 32 + (lane >> 2);    // instr0 row; instr1 = r0+16
    const int r1 = r0 + 16;
    const int c  = lane & 3;
    const int cs0 = c ^ ((r0 >> 1) & 3);    // swizzled global chunk for LDS slot (r0,c)
    const int cs1 = c ^ ((r1 >> 1) & 3);
    const u16* pa0 = A  + (size_t)(bm + r0) * K + cs0 * 8;
    const u16* pa1 = A  + (size_t)(bm + r1) * K + cs1 * 8;
    const u16* pb0 = Bt + (size_t)(bn + r0) * K + cs0 * 8;
    const u16* pb1 = Bt + (size_t)(bn + r1) * K + cs1 * 8;
    u16* la0 = &Asl[(size_t)w * 1024];      // wave-uniform LDS bases
    u16* la1 = &Asl[(size_t)w * 1024 + 512];
    u16* lb0 = &Bsl[(size_t)w * 1024];
    u16* lb1 = &Bsl[(size_t)w * 1024 + 512];

    // ---- fragment LDS offsets (constant per lane) ----
    const int q  = lane >> 4;               // k-chunk 0..3
    const int fr = lane & 15;               // row within 16x16 tile
    int offA[4], offB[4];
#pragma unroll
    for (int i = 0; i < 4; i++) {
        int ra = wm + i * 16 + fr;
        offA[i] = ra * 32 + ((q ^ ((ra >> 1) & 3)) << 3);
        int rb = wn + i * 16 + fr;
        offB[i] = rb * 32 + ((q ^ ((rb >> 1) & 3)) << 3);
    }

    f32x4 acc[4][4] = {};

    const int nk = K >> 5;
    for (int kt = 0; kt < nk; kt++) {
        __syncthreads();                    // prev-iter LDS reads complete
        __builtin_amdgcn_global_load_lds(
            (const __attribute__((address_space(1))) void*)pa0,
            (__attribute__((address_space(3))) void*)la0, 16, 0, 0);
        __builtin_amdgcn_global_load_lds(
            (const __attribute__((address_space(1))) void*)pa1,
            (__attribute__((address_space(3))) void*)la1, 16, 0, 0);
        __builtin_amdgcn_global_load_lds(
            (const __attribute__((address_space(1))) void*)pb0,
            (__attribute__((address_space(3))) void*)lb0, 16, 0, 0);
        __builtin_amdgcn_global_load_lds(
            (const __attribute__((address_space(1))) void*)pb1,
            (__attribute__((address_space(3))) void*)lb1, 16, 0, 0);
        pa0 += 32; pa1 += 32; pb0 += 32; pb1 += 32;
        __syncthreads();                    // staging complete (vmcnt drained)

        bf16x8 a[4], b[4];
#pragma unroll
        for (int i = 0; i < 4; i++) a[i] = *(const bf16x8*)&Asl[offA[i]];
#pragma unroll
        for (int i = 0; i < 4; i++) b[i] = *(const bf16x8*)&Bsl[offB[i]];
#pragma unroll
        for (int mi = 0; mi < 4; mi++)
#pragma unroll
            for (int ni = 0; ni < 4; ni++)
                acc[mi][ni] = __builtin_amdgcn_mfma_f32_16x16x32_bf16(
                    a[mi], b[ni], acc[mi][ni], 0, 0, 0);
    }

    // ---- epilogue. C/D layout: col = lane&15, row = (lane>>4)*4 + reg ----
    const int erow0 = bm + wm + ((lane >> 4) << 2);
    const int ecol0 = bn + wn + (lane & 15);
#pragma unroll
    for (int ni = 0; ni < 4; ni++) {
        const int ccol = ecol0 + ni * 16;
        const float bv = bias[ccol];
#pragma unroll
        for (int mi = 0; mi < 4; mi++) {
#pragma unroll
            for (int r = 0; r < 4; r++) {
                const size_t idx = (size_t)(erow0 + mi * 16 + r) * Nn + ccol;
                float v = acc[mi][ni][r] + bv;
                if (EPI == 1) v += res[idx];
                if (EPI == 2) {
                    v = 0.5f * v * (1.0f + erff(v * 0.70710678118f));
                    ((u16*)Cout)[idx] = f2bf(v);
                } else {
                    ((float*)Cout)[idx] = v;
                }
            }
        }
    }
}

// ---------------------------------------------------------------------------
// Flash-style attention, fp32 vector ALU; writes bf16 output.
// One 256-thread block per (h, q-tile of 64, b). 64x64 K/V tiles in LDS.
// qkv layout: [B, N, 3*Dm], col = which*Dm + h*DHd + d.
// ---------------------------------------------------------------------------
__global__ __launch_bounds__(256) void fattn_kernel(
    const float* __restrict__ qkv, const float* __restrict__ sbias,
    u16* __restrict__ out)
{
    __shared__ float Qs[64][68];   // [d][i]  (transposed)
    __shared__ float Ks[64][68];   // [d][m]  (transposed); reused as Ps[m][i]
    __shared__ float Vs[64][68];   // [m][d]

    const int tid = threadIdx.x;
    const int idx = blockIdx.x;         // ((h*32 + qt)*4 + b)
    const int b  = idx & 3;
    const int g  = idx >> 2;
    const int qt = g & 31;
    const int h  = g >> 5;
    const int n0 = qt * 64;

    const int tx = tid & 15, ty = tid >> 4;
    const size_t qkbase = (size_t)b * Nseq * (3 * Dm);

    for (int f = tid; f < 1024; f += 256) {
        const int i = f >> 4, d4 = (f & 15) * 4;
        float4 v = *(const float4*)&qkv[qkbase + (size_t)(n0 + i) * (3*Dm) + h*DHd + d4];
        Qs[d4+0][i] = v.x; Qs[d4+1][i] = v.y; Qs[d4+2][i] = v.z; Qs[d4+3][i] = v.w;
    }

    float O[4][4] = {};
    float mrow[4] = {-1e30f, -1e30f, -1e30f, -1e30f};
    float lrow[4] = {};

    for (int kt = 0; kt < 32; kt++) {
        __syncthreads();
        for (int f = tid; f < 1024; f += 256) {
            const int m = f >> 4, d4 = (f & 15) * 4;
            const size_t base = qkbase + (size_t)(kt*64 + m) * (3*Dm) + h*DHd + d4;
            float4 kv = *(const float4*)&qkv[base + Dm];
            float4 vv = *(const float4*)&qkv[base + 2*Dm];
            Ks[d4+0][m] = kv.x; Ks[d4+1][m] = kv.y; Ks[d4+2][m] = kv.z; Ks[d4+3][m] = kv.w;
            *(float4*)&Vs[m][d4] = vv;
        }
        __syncthreads();

        float S[4][4] = {};
#pragma unroll 16
        for (int d = 0; d < 64; d++) {
            float4 av = *(const float4*)&Qs[d][ty*4];
            float4 bv = *(const float4*)&Ks[d][tx*4];
            S[0][0] += av.x*bv.x; S[0][1] += av.x*bv.y; S[0][2] += av.x*bv.z; S[0][3] += av.x*bv.w;
            S[1][0] += av.y*bv.x; S[1][1] += av.y*bv.y; S[1][2] += av.y*bv.z; S[1][3] += av.y*bv.w;
            S[2][0] += av.z*bv.x; S[2][1] += av.z*bv.y; S[2][2] += av.z*bv.z; S[2][3] += av.z*bv.w;
            S[3][0] += av.w*bv.x; S[3][1] += av.w*bv.y; S[3][2] += av.w*bv.z; S[3][3] += av.w*bv.w;
        }

#pragma unroll
        for (int i = 0; i < 4; i++) {
            float4 bb = *(const float4*)&sbias[((size_t)h*Nseq + (n0+ty*4+i))*Nseq + kt*64 + tx*4];
            S[i][0] = S[i][0]*0.125f + bb.x;
            S[i][1] = S[i][1]*0.125f + bb.y;
            S[i][2] = S[i][2]*0.125f + bb.z;
            S[i][3] = S[i][3]*0.125f + bb.w;
        }

#pragma unroll
        for (int i = 0; i < 4; i++) {
            float tmax = fmaxf(fmaxf(S[i][0], S[i][1]), fmaxf(S[i][2], S[i][3]));
            tmax = fmaxf(tmax, __shfl_xor(tmax, 1, 64));
            tmax = fmaxf(tmax, __shfl_xor(tmax, 2, 64));
            tmax = fmaxf(tmax, __shfl_xor(tmax, 4, 64));
            tmax = fmaxf(tmax, __shfl_xor(tmax, 8, 64));
            const float mnew = fmaxf(mrow[i], tmax);
            const float alpha = __expf(mrow[i] - mnew);
            float ssum = 0.f;
#pragma unroll
            for (int j = 0; j < 4; j++) {
                S[i][j] = __expf(S[i][j] - mnew);
                ssum += S[i][j];
            }
            ssum += __shfl_xor(ssum, 1, 64);
            ssum += __shfl_xor(ssum, 2, 64);
            ssum += __shfl_xor(ssum, 4, 64);
            ssum += __shfl_xor(ssum, 8, 64);
            lrow[i] = lrow[i]*alpha + ssum;
            mrow[i] = mnew;
            O[i][0] *= alpha; O[i][1] *= alpha; O[i][2] *= alpha; O[i][3] *= alpha;
        }

        __syncthreads();
#pragma unroll
        for (int i = 0; i < 4; i++)
#pragma unroll
            for (int j = 0; j < 4; j++)
                Ks[tx*4+j][ty*4+i] = S[i][j];
        __syncthreads();

#pragma unroll 16
        for (int m = 0; m < 64; m++) {
            float4 av = *(const float4*)&Ks[m][ty*4];
            float4 bv = *(const float4*)&Vs[m][tx*4];
            O[0][0] += av.x*bv.x; O[0][1] += av.x*bv.y; O[0][2] += av.x*bv.z; O[0][3] += av.x*bv.w;
            O[1][0] += av.y*bv.x; O[1][1] += av.y*bv.y; O[1][2] += av.y*bv.z; O[1][3] += av.y*bv.w;
            O[2][0] += av.z*bv.x; O[2][1] += av.z*bv.y; O[2][2] += av.z*bv.z; O[2][3] += av.z*bv.w;
            O[3][0] += av.w*bv.x; O[3][1] += av.w*bv.y; O[3][2] += av.w*bv.z; O[3][3] += av.w*bv.w;
        }
    }

#pragma unroll
    for (int i = 0; i < 4; i++) {
        const float invl = 1.0f / lrow[i];
        ushort4 o;
        o.x = f2bf(O[i][0]*invl); o.y = f2bf(O[i][1]*invl);
        o.z = f2bf(O[i][2]*invl); o.w = f2bf(O[i][3]*invl);
        *(ushort4*)&out[(size_t)(b*Nseq + n0 + ty*4 + i)*Dm + h*DHd + tx*4] = o;
    }
}

// ---------------------------------------------------------------------------
// Workspace (<=160MB):
//   [0,96MB)    qkv fp32 (dead after fattn) / hidden bf16 64MB (FF phase)
//   [96,112MB)  normed bf16 (ln1 out; reused for ln2 out)
//   [112,128MB) attn bf16
//   [128,152MB) transposed bf16 weights: qkv 6MB | out 2MB | ff1 8MB | ff2 8MB
// ---------------------------------------------------------------------------
extern "C" void kernel_launch(void* const* d_in, const int* in_sizes, int n_in,
                              void* d_out, int out_size, void* d_ws, size_t ws_size,
                              hipStream_t stream)
{
    const float* x     = (const float*)d_in[0];
    const float* sbias = (const float*)d_in[1];
    const float* ln1g  = (const float*)d_in[2];
    const float* ln1b  = (const float*)d_in[3];
    const float* ln2g  = (const float*)d_in[4];
    const float* ln2b  = (const float*)d_in[5];
    const float* W_qkv = (const float*)d_in[6];
    const float* b_qkv = (const float*)d_in[7];
    const float* W_out = (const float*)d_in[8];
    const float* b_out = (const float*)d_in[9];
    const float* W_ff1 = (const float*)d_in[10];
    const float* b_ff1 = (const float*)d_in[11];
    const float* W_ff2 = (const float*)d_in[12];
    const float* b_ff2 = (const float*)d_in[13];
    float* out = (float*)d_out;

    char* ws = (char*)d_ws;
    const size_t MB = 1024ull * 1024;
    float* qkv    = (float*)ws;
    u16*   hidden = (u16*)ws;
    u16*   normed = (u16*)(ws + 96 * MB);
    u16*   attn   = (u16*)(ws + 112 * MB);
    u16*   Wqkv_t = (u16*)(ws + 128 * MB);
    u16*   Wout_t = (u16*)(ws + 134 * MB);
    u16*   Wff1_t = (u16*)(ws + 136 * MB);
    u16*   Wff2_t = (u16*)(ws + 144 * MB);

    const int M = Bsz * Nseq;   // 8192

    // 0. weight convert+transpose -> [N][K] bf16
    tcvt_kernel<<<dim3(3*Dm/32, Dm/32), 256, 0, stream>>>(W_qkv, Wqkv_t, Dm, 3*Dm);
    tcvt_kernel<<<dim3(Dm/32,   Dm/32), 256, 0, stream>>>(W_out, Wout_t, Dm, Dm);
    tcvt_kernel<<<dim3(DFFd/32, Dm/32), 256, 0, stream>>>(W_ff1, Wff1_t, Dm, DFFd);
    tcvt_kernel<<<dim3(Dm/32, DFFd/32), 256, 0, stream>>>(W_ff2, Wff2_t, DFFd, Dm);

    // 1. ln1(x) -> normed (bf16)
    ln_kernel<1><<<M, 256, 0, stream>>>(x, ln1g, ln1b, normed);
    // 2. qkv = normed @ W_qkv + b_qkv   (fp32 out for attention)
    bgemm_kernel<0><<<dim3(3*Dm/128, M/128), 256, 0, stream>>>(
        normed, Wqkv_t, b_qkv, nullptr, qkv, M, 3*Dm, Dm);
    // 3. flash attention -> attn (bf16)
    fattn_kernel<<<Hh * 32 * Bsz, 256, 0, stream>>>(qkv, sbias, attn);
    // 4. x1 = x + attn @ W_out + b_out -> d_out (fp32)
    bgemm_kernel<1><<<dim3(Dm/128, M/128), 256, 0, stream>>>(
        attn, Wout_t, b_out, x, out, M, Dm, Dm);
    // 5. ln2(x1) -> normed (bf16)
    ln_kernel<1><<<M, 256, 0, stream>>>(out, ln2g, ln2b, normed);
    // 6. hidden = gelu(normed @ W_ff1 + b_ff1) (bf16)
    bgemm_kernel<2><<<dim3(DFFd/128, M/128), 256, 0, stream>>>(
        normed, Wff1_t, b_ff1, nullptr, hidden, M, DFFd, Dm);
    // 7. out = x1 + hidden @ W_ff2 + b_ff2  (in-place on d_out)
    bgemm_kernel<1><<<dim3(Dm/128, M/128), 256, 0, stream>>>(
        hidden, Wff2_t, b_ff2, out, out, M, Dm, DFFd);
}